// Round 16
// baseline (171.274 us; speedup 1.0000x reference)
//
#include <hip/hip_runtime.h>
#include <math.h>

typedef _Float16 half8 __attribute__((ext_vector_type(8)));
typedef float    f32x4 __attribute__((ext_vector_type(4)));
typedef unsigned int u32;
typedef unsigned long long u64;
typedef unsigned short u16;

#define BIGV 1e30f
#define RQ 37                 // uint2 per ring row (296B: 256B window + 32B mirror + 8 pad)
#define PAIRQ (64 * RQ)       // 2368 uint2 per pair

__device__ __forceinline__ u32 dpp_shr1(u32 oldv, u32 src) {
  return (u32)__builtin_amdgcn_update_dpp((int)oldv, (int)src, 0x138, 0xF, 0xF, false);
}
__device__ __forceinline__ float cvtlo(u32 v) {
  union { u16 u; _Float16 h; } c; c.u = (u16)v; return (float)c.h;
}
__device__ __forceinline__ u16 f2h(float f) {
  union { _Float16 h; u16 u; } c; c.h = (_Float16)f; return c.u;
}
__device__ __forceinline__ u32 pkrtz(float a, float b) {
  auto v = __builtin_amdgcn_cvt_pkrtz(a, b);
  union { decltype(v) h; u32 u; } c; c.h = v; return c.u;
}
__device__ __forceinline__ u32 funnel16(u32 hi, u32 lo, u32 sh) {
  return (u32)(((((u64)hi) << 32) | (u64)lo) >> sh);   // v_alignbit
}

// Fillability test: 8 pairs/block, 128 blocks, 12 waves. SIMD s hosts C(pair s),
// C(pair s+4), P — two consumer chains per SIMD interleave each other's stalls.
// Producers read x from global (coalesced, L2-hot) with nb-skewed tile schedule
// (row-group nb produces tile T0/16-nb) -> write-read slot diffs {1..6} mod 8 != 0.
__global__ __launch_bounds__(768) void dtw_2c(
    const float* __restrict__ x,      // (16,16,1024)
    const float* __restrict__ patts,  // (64,16,64)
    float* __restrict__ out,          // (16,64,64,64)
    float wd) {
  __shared__ uint2 ring2[8 * PAIRQ];   // 151552 B
  __shared__ u16   x2h16[1024];        // 2 KB

  const int tid = threadIdx.x, lane = tid & 63, wv = tid >> 6;
  const int b = blockIdx.x >> 3, pg = blockIdx.x & 7;
  const int le = lane & 15, kq = lane >> 4;
  const float* xb = x + b * (16 * 1024);

  // ---- stage x2 only (x itself read from global by producers) ----
  for (int t = tid; t < 1024; t += 768) {
    float s2 = 0.f;
#pragma unroll
    for (int d = 0; d < 16; ++d) { float f = xb[d * 1024 + t]; s2 = fmaf(f, f, s2); }
    x2h16[t] = f2h(s2);
  }
  __syncthreads();   // B0

#define PRODUCE(RB, BF, T0) { \
    _Pragma("unroll") \
    for (int nb_ = 0; nb_ < 4; ++nb_) { \
      int t0n_ = (T0) - 16 * nb_; \
      if ((u32)t0n_ < 1024u) { \
        uint4 aq_; \
        if (kq < 2) { \
          const float* xp_ = xb + (8 * kq) * 1024 + t0n_ + le; \
          aq_.x = pkrtz(xp_[0],    xp_[1024]); \
          aq_.y = pkrtz(xp_[2048], xp_[3072]); \
          aq_.z = pkrtz(xp_[4096], xp_[5120]); \
          aq_.w = pkrtz(xp_[6144], xp_[7168]); \
        } else if (kq == 2) { \
          aq_ = make_uint4((u32)x2h16[t0n_ + le] | 0x3C000000u, 0u, 0u, 0u); \
        } else { aq_ = make_uint4(0u, 0u, 0u, 0u); } \
        union { uint4 q; half8 h; } au_; au_.q = aq_; \
        f32x4 c_ = {0.f, 0.f, 0.f, 0.f}; \
        c_ = __builtin_amdgcn_mfma_f32_16x16x32_f16(au_.h, (BF)[nb_], c_, 0, 0, 0); \
        float d0_ = __builtin_amdgcn_sqrtf(fmaxf(c_[0], 1e-12f)); \
        float d1_ = __builtin_amdgcn_sqrtf(fmaxf(c_[1], 1e-12f)); \
        float d2_ = __builtin_amdgcn_sqrtf(fmaxf(c_[2], 1e-12f)); \
        float d3_ = __builtin_amdgcn_sqrtf(fmaxf(c_[3], 1e-12f)); \
        u32 coln_ = (u32)(((((T0) >> 4) - nb_) & 7) * 32 + 8 * kq); \
        int wb_ = (RB) + 37 * le + 592 * nb_ + (int)(coln_ >> 3); \
        uint2 st_; st_.x = pkrtz(d0_, d1_); st_.y = pkrtz(d2_, d3_); \
        ring2[wb_] = st_; \
        if (coln_ < 32u) ring2[wb_ + 32] = st_; \
      } \
    } }

  if (wv >= 8) {
    // ================= PRODUCER (2 pairs per wave) =================
    const int j = wv - 8;
    const int prA = 2 * j, prB = 2 * j + 1;
    const int rbA = prA * PAIRQ, rbB = prB * PAIRQ;
    half8 bfA[4], bfB[4];
#pragma unroll
    for (int side = 0; side < 2; ++side) {
      const float* pp = patts + (pg * 8 + (side ? prB : prA)) * (16 * 64);
      half8* bf = side ? bfB : bfA;
#pragma unroll
      for (int nb = 0; nb < 4; ++nb) {
        float pv[8]; float part = 0.f;
#pragma unroll
        for (int jj = 0; jj < 8; ++jj) {
          float f = (kq < 2) ? pp[(8 * kq + jj) * 64 + nb * 16 + le] : 0.f;
          pv[jj] = f; part = fmaf(f, f, part);
        }
        part += __shfl_xor(part, 16, 64);
        part += __shfl_xor(part, 32, 64);
        u32 wd0 = pkrtz(-2.f * pv[0], -2.f * pv[1]);
        u32 wd1 = pkrtz(-2.f * pv[2], -2.f * pv[3]);
        u32 wd2 = pkrtz(-2.f * pv[4], -2.f * pv[5]);
        u32 wd3 = pkrtz(-2.f * pv[6], -2.f * pv[7]);
        if (kq == 2) { wd0 = 0x3C00u | ((u32)f2h(part) << 16); wd1 = 0; wd2 = 0; wd3 = 0; }
        union { uint4 q; half8 h; } bu; bu.q = make_uint4(wd0, wd1, wd2, wd3);
        bf[nb] = bu.h;
      }
    }
    // prologue: tiles T0/16 in {0..3} for both pairs (lead 4)
    PRODUCE(rbA, bfA, 0);  PRODUCE(rbA, bfA, 16); PRODUCE(rbA, bfA, 32); PRODUCE(rbA, bfA, 48);
    PRODUCE(rbB, bfB, 0);  PRODUCE(rbB, bfB, 16); PRODUCE(rbB, bfB, 32); PRODUCE(rbB, bfB, 48);
    __syncthreads();   // B1
#pragma unroll 1
    for (int k = 0; k < 34; ++k) {
      if (k < 32) {
        PRODUCE(rbA, bfA, 32 * k + 64); PRODUCE(rbA, bfA, 32 * k + 80);
        PRODUCE(rbB, bfB, 32 * k + 64); PRODUCE(rbB, bfB, 32 * k + 80);
      }
      __syncthreads();
    }

  } else {
    // ================= CONSUMER (R9-validated machinery) =================
    const int pr = wv;
    const int p = pg * 8 + pr;
    const int rcbase = pr * PAIRQ + RQ * lane;
    int colc = (((0 - lane) >> 2) << 3) & 255;
    const int ph = (0 - lane) & 3;
    const u32 shv = (u32)((ph & 1) * 16);
    const bool sel2 = (ph & 2) != 0;
    float prev = BIGV, shA = BIGV, shB = BIGV, pend = 0.f;
    const int bigbits = __float_as_int(BIGV);
    float* oprow = out + ((b * 64 + p) * 64 + lane) * 64;

#define LOADQ(Q0,Q1,Q2,Q3,Q4) { int ci_ = rcbase + (colc >> 3); \
    Q0 = ring2[ci_];     Q1 = ring2[ci_ + 1]; Q2 = ring2[ci_ + 2]; \
    Q3 = ring2[ci_ + 3]; Q4 = ring2[ci_ + 4]; \
    colc = (colc + 32) & 255; }

#define SHIFT(curv) { shB = shA; \
    shA = __int_as_float((int)dpp_shr1((u32)bigbits, (u32)__float_as_int(curv))); \
    prev = (curv); }

#define STEP_PRO(S, D) { float dist_ = (D); \
    float m_ = fminf(fminf(prev, shA), shB); \
    float ms_ = (m_ >= 0.5e30f) ? 0.f : m_; \
    float val_ = fmaf(wd, ms_, dist_); \
    int t_ = (S) - lane; float cur_ = (t_ >= 0) ? val_ : BIGV; \
    SHIFT(cur_); }

#define STEP_MAIN(S, D) { float dist_ = (D); \
    float m_ = fminf(fminf(prev, shA), shB); \
    float cur_ = fmaf(wd, m_, dist_); \
    SHIFT(cur_); }

#define STEP_EPI2(S, D) { float dist_ = (D); \
    float m_ = fminf(fminf(prev, shA), shB); \
    float val_ = fmaf(wd, m_, dist_); \
    int t_ = (S) - lane; \
    if ((t_ & 1) == 0) { pend = val_; } \
    else if ((u32)(t_ - 961) < 63u) \
      *(float2*)(oprow + (t_ - 961)) = make_float2(pend, val_); \
    SHIFT(val_); }

#define STEP_EPI3(S, D) { float dist_ = (D); \
    float m_ = fminf(fminf(prev, shA), shB); \
    float val_ = fmaf(wd, m_, dist_); \
    int t_ = (S) - lane; float cur_ = (t_ <= 1023) ? val_ : BIGV; \
    if ((t_ & 1) == 0) { pend = val_; } \
    else if ((u32)(t_ - 961) < 63u) \
      *(float2*)(oprow + (t_ - 961)) = make_float2(pend, val_); \
    SHIFT(cur_); }

#define EXTRACT8(Q0, Q1, Q2, Q3, Q4) \
    u32 W0_ = sel2 ? Q0.y : Q0.x, W1_ = sel2 ? Q1.x : Q0.y, \
        W2_ = sel2 ? Q1.y : Q1.x, W3_ = sel2 ? Q2.x : Q1.y, \
        W4_ = sel2 ? Q2.y : Q2.x, W5_ = sel2 ? Q3.x : Q2.y, \
        W6_ = sel2 ? Q3.y : Q3.x, W7_ = sel2 ? Q4.x : Q3.y, \
        W8_ = sel2 ? Q4.y : Q4.x; \
    u32 A0 = funnel16(W1_, W0_, shv), A1 = funnel16(W2_, W1_, shv), \
        A2 = funnel16(W3_, W2_, shv), A3 = funnel16(W4_, W3_, shv), \
        A4 = funnel16(W5_, W4_, shv), A5 = funnel16(W6_, W5_, shv), \
        A6 = funnel16(W7_, W6_, shv), A7 = funnel16(W8_, W7_, shv);

#define S16(S0, STP) \
    STP((S0)+0,  cvtlo(A0)); STP((S0)+1,  cvtlo(A0 >> 16)); \
    STP((S0)+2,  cvtlo(A1)); STP((S0)+3,  cvtlo(A1 >> 16)); \
    STP((S0)+4,  cvtlo(A2)); STP((S0)+5,  cvtlo(A2 >> 16)); \
    STP((S0)+6,  cvtlo(A3)); STP((S0)+7,  cvtlo(A3 >> 16)); \
    STP((S0)+8,  cvtlo(A4)); STP((S0)+9,  cvtlo(A4 >> 16)); \
    STP((S0)+10, cvtlo(A5)); STP((S0)+11, cvtlo(A5 >> 16)); \
    STP((S0)+12, cvtlo(A6)); STP((S0)+13, cvtlo(A6 >> 16)); \
    STP((S0)+14, cvtlo(A7)); STP((S0)+15, cvtlo(A7 >> 16));

#define SET_PRO(S0)  S16(S0, STEP_PRO)
#define SET_MAIN(S0) S16(S0, STEP_MAIN)
#define SET_EPI2(S0) S16(S0, STEP_EPI2)
#define SET_EPI3(S0) S16(S0, STEP_EPI3)

#define PHASE(C0,C1,C2,C3,C4,C5,C6,C7,C8,C9, L0,L1,L2,L3,L4,L5,L6,L7,L8,L9, S0, SETM) { \
    LOADQ(L0,L1,L2,L3,L4); LOADQ(L5,L6,L7,L8,L9); \
    { EXTRACT8(C0,C1,C2,C3,C4); SETM(S0); } \
    { EXTRACT8(C5,C6,C7,C8,C9); SETM((S0)+16); } \
    __builtin_amdgcn_s_barrier(); }

    __builtin_amdgcn_s_barrier();   // B1: tiles 0-3 ready
    uint2 a0,a1,a2,a3,a4,a5,a6,a7,a8,a9;
    uint2 b0,b1,b2,b3,b4,b5,b6,b7,b8,b9;
    LOADQ(a0,a1,a2,a3,a4); LOADQ(a5,a6,a7,a8,a9);   // tiles 0,1

    PHASE(a0,a1,a2,a3,a4,a5,a6,a7,a8,a9, b0,b1,b2,b3,b4,b5,b6,b7,b8,b9, 0,  SET_PRO);
    PHASE(b0,b1,b2,b3,b4,b5,b6,b7,b8,b9, a0,a1,a2,a3,a4,a5,a6,a7,a8,a9, 32, SET_PRO);
#pragma unroll 1
    for (int j = 1; j < 15; ++j) {
      PHASE(a0,a1,a2,a3,a4,a5,a6,a7,a8,a9, b0,b1,b2,b3,b4,b5,b6,b7,b8,b9, 64*j,      SET_MAIN);
      PHASE(b0,b1,b2,b3,b4,b5,b6,b7,b8,b9, a0,a1,a2,a3,a4,a5,a6,a7,a8,a9, 64*j + 32, SET_MAIN);
    }
    PHASE(a0,a1,a2,a3,a4,a5,a6,a7,a8,a9, b0,b1,b2,b3,b4,b5,b6,b7,b8,b9, 960,  SET_EPI2);
    PHASE(b0,b1,b2,b3,b4,b5,b6,b7,b8,b9, a0,a1,a2,a3,a4,a5,a6,a7,a8,a9, 992,  SET_EPI2);
    PHASE(a0,a1,a2,a3,a4,a5,a6,a7,a8,a9, b0,b1,b2,b3,b4,b5,b6,b7,b8,b9, 1024, SET_EPI3);
    PHASE(b0,b1,b2,b3,b4,b5,b6,b7,b8,b9, a0,a1,a2,a3,a4,a5,a6,a7,a8,a9, 1056, SET_EPI3);
  }
}

extern "C" void kernel_launch(void* const* d_in, const int* in_sizes, int n_in,
                              void* d_out, int out_size, void* d_ws, size_t ws_size,
                              hipStream_t stream) {
  const float* x     = (const float*)d_in[0];
  const float* patts = (const float*)d_in[1];
  float* out         = (float*)d_out;
  const float w = (float)exp(log(0.1) / 64.0);
  dim3 grid(128), block(768);
  hipLaunchKernelGGL(dtw_2c, grid, block, 0, stream, x, patts, out, w);
}